// Round 1
// baseline (10557.327 us; speedup 1.0000x reference)
//
#include <hip/hip_runtime.h>

#define DIM 64

__global__ void deg_kernel(const int* __restrict__ dst, float* __restrict__ deg, int E) {
    int i = blockIdx.x * blockDim.x + threadIdx.x;
    if (i < E) atomicAdd(&deg[dst[i]], 1.0f);
}

__global__ void dinv_kernel(const float* __restrict__ deg, float* __restrict__ dinv, int N) {
    int i = blockIdx.x * blockDim.x + threadIdx.x;
    if (i < N) {
        float d = deg[i];
        dinv[i] = d > 0.0f ? rsqrtf(d) : 0.0f;
    }
}

__global__ void norm_kernel(const int* __restrict__ src, const int* __restrict__ dst,
                            const float* __restrict__ dinv, float* __restrict__ norm, int E) {
    int i = blockIdx.x * blockDim.x + threadIdx.x;
    if (i < E) norm[i] = dinv[src[i]] * dinv[dst[i]];
}

// One thread per (edge, 4-float chunk): 16 threads cover an edge's 64-dim row.
__global__ void scatter_kernel(const int* __restrict__ src, const int* __restrict__ dst,
                               const float* __restrict__ norm,
                               const float* __restrict__ emb_in, float* __restrict__ emb_out,
                               int E) {
    long long tid = (long long)blockIdx.x * blockDim.x + threadIdx.x;
    long long total = (long long)E * 16;
    if (tid >= total) return;
    int e = (int)(tid >> 4);
    int q = (int)(tid & 15);
    int s = src[e];
    int d = dst[e];
    float w = norm[e];
    const float4 g = *(const float4*)(emb_in + (long long)s * DIM + q * 4);
    float* o = emb_out + (long long)d * DIM + q * 4;
    atomicAdd(o + 0, w * g.x);
    atomicAdd(o + 1, w * g.y);
    atomicAdd(o + 2, w * g.z);
    atomicAdd(o + 3, w * g.w);
}

__global__ void add_kernel(float* __restrict__ acc, const float* __restrict__ x, int n4) {
    int i = blockIdx.x * blockDim.x + threadIdx.x;
    if (i < n4) {
        float4 a = ((const float4*)acc)[i];
        float4 b = ((const float4*)x)[i];
        a.x += b.x; a.y += b.y; a.z += b.z; a.w += b.w;
        ((float4*)acc)[i] = a;
    }
}

__global__ void add_scale_kernel(float* __restrict__ acc, const float* __restrict__ x, int n4) {
    int i = blockIdx.x * blockDim.x + threadIdx.x;
    if (i < n4) {
        float4 a = ((const float4*)acc)[i];
        float4 b = ((const float4*)x)[i];
        a.x = (a.x + b.x) * 0.25f;
        a.y = (a.y + b.y) * 0.25f;
        a.z = (a.z + b.z) * 0.25f;
        a.w = (a.w + b.w) * 0.25f;
        ((float4*)acc)[i] = a;
    }
}

static inline size_t align256(size_t x) { return (x + 255) & ~(size_t)255; }

extern "C" void kernel_launch(void* const* d_in, const int* in_sizes, int n_in,
                              void* d_out, int out_size, void* d_ws, size_t ws_size,
                              hipStream_t stream) {
    const int*   edge = (const int*)d_in[0];
    const float* emb0 = (const float*)d_in[1];
    const int E = in_sizes[0] / 2;
    const int N = in_sizes[1] / DIM;
    const int* src = edge;
    const int* dst = edge + E;

    // workspace carve-up
    char* ws = (char*)d_ws;
    float* deg  = (float*)ws;  ws += align256((size_t)N * sizeof(float));
    float* dinv = (float*)ws;  ws += align256((size_t)N * sizeof(float));
    float* norm = (float*)ws;  ws += align256((size_t)E * sizeof(float));
    float* embA = (float*)ws;  ws += align256((size_t)N * DIM * sizeof(float));
    float* embB = (float*)ws;  ws += align256((size_t)N * DIM * sizeof(float));

    float* out_emb0 = (float*)d_out;                     // first output: emb0 copy
    float* acc      = out_emb0 + (size_t)N * DIM;        // second output: running sum

    const size_t emb_bytes = (size_t)N * DIM * sizeof(float);
    const int n4 = N * DIM / 4;

    // degrees + norm
    hipMemsetAsync(deg, 0, (size_t)N * sizeof(float), stream);
    deg_kernel<<<(E + 255) / 256, 256, 0, stream>>>(dst, deg, E);
    dinv_kernel<<<(N + 255) / 256, 256, 0, stream>>>(deg, dinv, N);
    norm_kernel<<<(E + 255) / 256, 256, 0, stream>>>(src, dst, dinv, norm, E);

    // outputs: emb0 copy, acc init = emb0
    hipMemcpyAsync(out_emb0, emb0, emb_bytes, hipMemcpyDeviceToDevice, stream);
    hipMemcpyAsync(acc,      emb0, emb_bytes, hipMemcpyDeviceToDevice, stream);

    const long long total = (long long)E * 16;
    const int sgrid = (int)((total + 255) / 256);

    const float* cur = emb0;
    float* buf[2] = { embA, embB };
    for (int l = 0; l < 3; ++l) {
        float* nxt = buf[l & 1];
        hipMemsetAsync(nxt, 0, emb_bytes, stream);
        scatter_kernel<<<sgrid, 256, 0, stream>>>(src, dst, norm, cur, nxt, E);
        if (l < 2)
            add_kernel<<<(n4 + 255) / 256, 256, 0, stream>>>(acc, nxt, n4);
        else
            add_scale_kernel<<<(n4 + 255) / 256, 256, 0, stream>>>(acc, nxt, n4);
        cur = nxt;
    }
}

// Round 2
// 1454.930 us; speedup vs baseline: 7.2562x; 7.2562x over previous
//
#include <hip/hip_runtime.h>

#define DIM 64

__global__ void deg_kernel(const int* __restrict__ dst, int* __restrict__ deg, int E) {
    int i = blockIdx.x * blockDim.x + threadIdx.x;
    if (i < E) atomicAdd(&deg[dst[i]], 1);
}

__global__ void dinv_kernel(const int* __restrict__ deg, float* __restrict__ dinv, int N) {
    int i = blockIdx.x * blockDim.x + threadIdx.x;
    if (i < N) {
        int d = deg[i];
        dinv[i] = d > 0 ? rsqrtf((float)d) : 0.0f;
    }
}

// Single-block exclusive scan of deg[0..N) -> row_start[0..N], row_start[N]=total.
__global__ void __launch_bounds__(1024) scan_kernel(const int* __restrict__ deg,
                                                    int* __restrict__ row_start, int N) {
    __shared__ int sums[1024];
    const int t = threadIdx.x;
    const int chunk = (N + 1023) / 1024;
    const int beg = t * chunk;
    const int end = min(beg + chunk, N);
    int s = 0;
    for (int i = beg; i < end; ++i) s += deg[i];
    sums[t] = s;
    __syncthreads();
    // Hillis-Steele inclusive scan over 1024 partials
    for (int off = 1; off < 1024; off <<= 1) {
        int v = sums[t];
        int add = (t >= off) ? sums[t - off] : 0;
        __syncthreads();
        sums[t] = v + add;
        __syncthreads();
    }
    int running = (t == 0) ? 0 : sums[t - 1];
    for (int i = beg; i < end; ++i) {
        row_start[i] = running;
        running += deg[i];
    }
    if (t == 0) row_start[N] = sums[1023];
}

__global__ void fill_kernel(const int* __restrict__ src, const int* __restrict__ dst,
                            int* __restrict__ cursor, int* __restrict__ csr_src, int E) {
    int i = blockIdx.x * blockDim.x + threadIdx.x;
    if (i < E) {
        int pos = atomicAdd(&cursor[dst[i]], 1);
        csr_src[pos] = src[i];
    }
}

// Pull-based aggregation: 16 threads per dst node, each handles a float4 chunk
// of the 64-dim row. Per edge: coalesced 256B read of emb_in[src] by the
// 16-lane group. Fuses acc update; optionally skips emb_out write (last layer).
__global__ void gather_kernel(const int* __restrict__ row_start,
                              const int* __restrict__ csr_src,
                              const float* __restrict__ dinv,
                              const float* __restrict__ emb_in,
                              float* __restrict__ emb_out,
                              float* __restrict__ acc,
                              int N, int last) {
    int tid = blockIdx.x * blockDim.x + threadIdx.x;
    int node = tid >> 4;
    int q = tid & 15;
    if (node >= N) return;
    const int beg = row_start[node];
    const int end = row_start[node + 1];
    const float di = dinv[node];
    float4 s = make_float4(0.f, 0.f, 0.f, 0.f);
    for (int i = beg; i < end; ++i) {
        int sIdx = csr_src[i];
        float w = di * dinv[sIdx];
        const float4 g = *(const float4*)(emb_in + (size_t)sIdx * DIM + q * 4);
        s.x = fmaf(w, g.x, s.x);
        s.y = fmaf(w, g.y, s.y);
        s.z = fmaf(w, g.z, s.z);
        s.w = fmaf(w, g.w, s.w);
    }
    const size_t o = (size_t)node * DIM + q * 4;
    if (!last) *(float4*)(emb_out + o) = s;
    float4 a = *(const float4*)(acc + o);
    if (last) {
        a.x = (a.x + s.x) * 0.25f;
        a.y = (a.y + s.y) * 0.25f;
        a.z = (a.z + s.z) * 0.25f;
        a.w = (a.w + s.w) * 0.25f;
    } else {
        a.x += s.x; a.y += s.y; a.z += s.z; a.w += s.w;
    }
    *(float4*)(acc + o) = a;
}

static inline size_t align256(size_t x) { return (x + 255) & ~(size_t)255; }

extern "C" void kernel_launch(void* const* d_in, const int* in_sizes, int n_in,
                              void* d_out, int out_size, void* d_ws, size_t ws_size,
                              hipStream_t stream) {
    const int*   edge = (const int*)d_in[0];
    const float* emb0 = (const float*)d_in[1];
    const int E = in_sizes[0] / 2;
    const int N = in_sizes[1] / DIM;
    const int* src = edge;
    const int* dst = edge + E;

    // workspace carve-up (~122 MB)
    char* ws = (char*)d_ws;
    int*   deg       = (int*)ws;   ws += align256((size_t)N * sizeof(int));
    int*   row_start = (int*)ws;   ws += align256((size_t)(N + 1) * sizeof(int));
    int*   cursor    = (int*)ws;   ws += align256((size_t)N * sizeof(int));
    float* dinv      = (float*)ws; ws += align256((size_t)N * sizeof(float));
    int*   csr_src   = (int*)ws;   ws += align256((size_t)E * sizeof(int));
    float* embA      = (float*)ws; ws += align256((size_t)N * DIM * sizeof(float));
    float* embB      = (float*)ws; ws += align256((size_t)N * DIM * sizeof(float));

    float* out_emb0 = (float*)d_out;
    float* acc      = out_emb0 + (size_t)N * DIM;

    const size_t emb_bytes = (size_t)N * DIM * sizeof(float);

    // degrees -> dinv
    hipMemsetAsync(deg, 0, (size_t)N * sizeof(int), stream);
    deg_kernel<<<(E + 255) / 256, 256, 0, stream>>>(dst, deg, E);
    dinv_kernel<<<(N + 255) / 256, 256, 0, stream>>>(deg, dinv, N);

    // CSR build: scan + cursor fill
    scan_kernel<<<1, 1024, 0, stream>>>(deg, row_start, N);
    hipMemcpyAsync(cursor, row_start, (size_t)N * sizeof(int), hipMemcpyDeviceToDevice, stream);
    fill_kernel<<<(E + 255) / 256, 256, 0, stream>>>(src, dst, cursor, csr_src, E);

    // outputs: emb0 copy, acc init = emb0
    hipMemcpyAsync(out_emb0, emb0, emb_bytes, hipMemcpyDeviceToDevice, stream);
    hipMemcpyAsync(acc,      emb0, emb_bytes, hipMemcpyDeviceToDevice, stream);

    const int gthreads = N * 16;
    const int ggrid = (gthreads + 255) / 256;

    // layer 1: emb0 -> embA ; layer 2: embA -> embB ; layer 3: embB -> (acc only)
    gather_kernel<<<ggrid, 256, 0, stream>>>(row_start, csr_src, dinv, emb0, embA, acc, N, 0);
    gather_kernel<<<ggrid, 256, 0, stream>>>(row_start, csr_src, dinv, embA, embB, acc, N, 0);
    gather_kernel<<<ggrid, 256, 0, stream>>>(row_start, csr_src, dinv, embB, nullptr, acc, N, 1);
}

// Round 3
// 585.590 us; speedup vs baseline: 18.0285x; 2.4846x over previous
//
#include <hip/hip_runtime.h>

#define DIM 64
#define BNODE_SHIFT 9                 // 512 nodes per bucket
#define BNODE (1 << BNODE_SHIFT)
#define MAXNB 512                     // max buckets (N <= 262144)
#define BIN_CHUNK 8192                // edges per block in hist/bin

__device__ inline float bf2f(unsigned short h) {
    return __uint_as_float(((unsigned int)h) << 16);
}
__device__ inline unsigned int f2bf2(float a, float b) {  // pack 2 floats -> 2 bf16 (RNE)
    unsigned int ua = __float_as_uint(a);
    unsigned int ub = __float_as_uint(b);
    ua = (ua + 0x7FFFu + ((ua >> 16) & 1u)) >> 16;
    ub = (ub + 0x7FFFu + ((ub >> 16) & 1u)) >> 16;
    return ua | (ub << 16);
}

// ---- Pass 1: global bucket histogram (bucket = dst >> 9) ----
__global__ void hist_kernel(const int* __restrict__ dst, int* __restrict__ bucket_count,
                            int E, int NB) {
    __shared__ int h[MAXNB];
    const int t = threadIdx.x;
    for (int i = t; i < MAXNB; i += blockDim.x) h[i] = 0;
    __syncthreads();
    const long long beg = (long long)blockIdx.x * BIN_CHUNK;
    for (int j = 0; j < BIN_CHUNK / 256; ++j) {
        long long idx = beg + j * 256 + t;
        if (idx < E) atomicAdd(&h[dst[idx] >> BNODE_SHIFT], 1);
    }
    __syncthreads();
    for (int b = t; b < NB; b += blockDim.x)
        if (h[b]) atomicAdd(&bucket_count[b], h[b]);
}

// ---- Pass 2: scan buckets -> bucket_base, bucket_cursor; row_start[N]=E ----
__global__ void __launch_bounds__(MAXNB) bucket_scan_kernel(
        const int* __restrict__ bucket_count, int* __restrict__ bucket_base,
        int* __restrict__ bucket_cursor, int* __restrict__ row_start,
        int NB, int N, int E) {
    __shared__ int s[MAXNB];
    const int t = threadIdx.x;
    int c = (t < NB) ? bucket_count[t] : 0;
    s[t] = c;
    __syncthreads();
    for (int off = 1; off < MAXNB; off <<= 1) {
        int v = s[t];
        int a = (t >= off) ? s[t - off] : 0;
        __syncthreads();
        s[t] = v + a;
        __syncthreads();
    }
    if (t < NB) {
        int excl = s[t] - c;
        bucket_base[t] = excl;
        bucket_cursor[t] = excl;
    }
    if (t == 0) {
        bucket_base[NB] = s[MAXNB - 1];
        row_start[N] = E;
    }
}

// ---- Pass 3: bin edges into buckets, packed 4B: src | (dstLocal<<18) ----
__global__ void bin_kernel(const int* __restrict__ src, const int* __restrict__ dst,
                           int* __restrict__ bucket_cursor, unsigned int* __restrict__ packed,
                           int E, int NB) {
    __shared__ int lhist[MAXNB];
    __shared__ int lbase[MAXNB];
    const int t = threadIdx.x;
    for (int i = t; i < MAXNB; i += blockDim.x) lhist[i] = 0;
    __syncthreads();
    const long long beg = (long long)blockIdx.x * BIN_CHUNK;
    for (int j = 0; j < BIN_CHUNK / 256; ++j) {
        long long idx = beg + j * 256 + t;
        if (idx < E) atomicAdd(&lhist[dst[idx] >> BNODE_SHIFT], 1);
    }
    __syncthreads();
    for (int b = t; b < NB; b += blockDim.x) {
        int c = lhist[b];
        lbase[b] = c ? atomicAdd(&bucket_cursor[b], c) : 0;
    }
    __syncthreads();
    for (int i = t; i < MAXNB; i += blockDim.x) lhist[i] = 0;
    __syncthreads();
    for (int j = 0; j < BIN_CHUNK / 256; ++j) {
        long long idx = beg + j * 256 + t;
        if (idx < E) {
            int d = dst[idx];
            int b = d >> BNODE_SHIFT;
            int lpos = atomicAdd(&lhist[b], 1);
            packed[lbase[b] + lpos] =
                (unsigned int)src[idx] | ((unsigned int)(d & (BNODE - 1)) << 18);
        }
    }
}

// ---- Pass 4: per-bucket exact CSR + degree outputs (one block per bucket) ----
__global__ void __launch_bounds__(BNODE) csr_kernel(
        const int* __restrict__ bucket_base, const unsigned int* __restrict__ packed,
        int* __restrict__ csr_src, int* __restrict__ row_start,
        float* __restrict__ dinv, float* __restrict__ rs, float* __restrict__ di2,
        int N) {
    __shared__ int hist[BNODE];
    __shared__ int s[BNODE];
    const int t = threadIdx.x;
    const int b = blockIdx.x;
    const int b0 = bucket_base[b];
    const int cnt = bucket_base[b + 1] - b0;
    hist[t] = 0;
    __syncthreads();
    for (int i = t; i < cnt; i += BNODE)
        atomicAdd(&hist[packed[b0 + i] >> 18], 1);
    __syncthreads();
    s[t] = hist[t];
    __syncthreads();
    for (int off = 1; off < BNODE; off <<= 1) {
        int v = s[t];
        int a = (t >= off) ? s[t - off] : 0;
        __syncthreads();
        s[t] = v + a;
        __syncthreads();
    }
    const int deg = hist[t];
    const int excl = s[t] - deg;
    const int node = (b << BNODE_SHIFT) + t;
    if (node < N) {
        row_start[node] = b0 + excl;
        float fd = (float)deg;
        float di = deg > 0 ? rsqrtf(fd) : 0.0f;
        dinv[node] = di;
        rs[node]   = deg > 0 ? sqrtf(fd) : 0.0f;
        di2[node]  = di * di;
    }
    __syncthreads();
    s[t] = excl;   // reuse as per-node cursor
    __syncthreads();
    for (int i = t; i < cnt; i += BNODE) {
        unsigned int p = packed[b0 + i];
        int lpos = atomicAdd(&s[p >> 18], 1);
        csr_src[b0 + lpos] = (int)(p & 0x3FFFFu);
    }
}

// ---- conv0: out_emb0 = emb0 (fp32 copy), S0 = bf16(dinv * emb0) ----
__global__ void conv0_kernel(const float* __restrict__ emb0, const float* __restrict__ dinv,
                             float* __restrict__ out_emb0, unsigned int* __restrict__ S0,
                             int n4) {
    int i = blockIdx.x * blockDim.x + threadIdx.x;
    if (i >= n4) return;
    float4 v = ((const float4*)emb0)[i];
    ((float4*)out_emb0)[i] = v;
    float w = dinv[i >> 4];
    uint2 o;
    o.x = f2bf2(w * v.x, w * v.y);
    o.y = f2bf2(w * v.z, w * v.w);
    ((uint2*)S0)[i] = o;
}

// ---- gather: S_out[dst] = bf16( di2[dst] * sum_{e->dst} S_in[src] ) ----
// 8 lanes per node; each lane owns an 8-element (16B bf16) chunk of the row.
__global__ void gather_kernel(const int* __restrict__ row_start,
                              const int* __restrict__ csr_src,
                              const float* __restrict__ di2,
                              const unsigned int* __restrict__ S_in,
                              unsigned int* __restrict__ S_out,
                              int N) {
    int tid = blockIdx.x * blockDim.x + threadIdx.x;
    int node = tid >> 3;
    int q = tid & 7;
    if (node >= N) return;
    const int beg = row_start[node];
    const int end = row_start[node + 1];
    float r0 = 0.f, r1 = 0.f, r2 = 0.f, r3 = 0.f, r4 = 0.f, r5 = 0.f, r6 = 0.f, r7 = 0.f;
    for (int i = beg; i < end; ++i) {
        int sIdx = csr_src[i];
        uint4 g = *(const uint4*)(S_in + (size_t)sIdx * (DIM / 2) + q * 4);
        r0 += bf2f((unsigned short)(g.x & 0xFFFF));
        r1 += bf2f((unsigned short)(g.x >> 16));
        r2 += bf2f((unsigned short)(g.y & 0xFFFF));
        r3 += bf2f((unsigned short)(g.y >> 16));
        r4 += bf2f((unsigned short)(g.z & 0xFFFF));
        r5 += bf2f((unsigned short)(g.z >> 16));
        r6 += bf2f((unsigned short)(g.w & 0xFFFF));
        r7 += bf2f((unsigned short)(g.w >> 16));
    }
    float w = di2[node];
    uint4 o;
    o.x = f2bf2(w * r0, w * r1);
    o.y = f2bf2(w * r2, w * r3);
    o.z = f2bf2(w * r4, w * r5);
    o.w = f2bf2(w * r6, w * r7);
    *(uint4*)(S_out + (size_t)node * (DIM / 2) + q * 4) = o;
}

// ---- combine: acc = 0.25 * (emb0 + rs[node]*(S1+S2+S3)) ----
__global__ void combine_kernel(const float* __restrict__ emb0, const float* __restrict__ rs,
                               const unsigned int* __restrict__ S1,
                               const unsigned int* __restrict__ S2,
                               const unsigned int* __restrict__ S3,
                               float* __restrict__ acc, int n4) {
    int i = blockIdx.x * blockDim.x + threadIdx.x;
    if (i >= n4) return;
    float4 e = ((const float4*)emb0)[i];
    uint2 a = ((const uint2*)S1)[i];
    uint2 b = ((const uint2*)S2)[i];
    uint2 c = ((const uint2*)S3)[i];
    float w = rs[i >> 4];
    float4 o;
    o.x = 0.25f * (e.x + w * (bf2f(a.x & 0xFFFF) + bf2f(b.x & 0xFFFF) + bf2f(c.x & 0xFFFF)));
    o.y = 0.25f * (e.y + w * (bf2f(a.x >> 16)   + bf2f(b.x >> 16)   + bf2f(c.x >> 16)));
    o.z = 0.25f * (e.z + w * (bf2f(a.y & 0xFFFF) + bf2f(b.y & 0xFFFF) + bf2f(c.y & 0xFFFF)));
    o.w = 0.25f * (e.w + w * (bf2f(a.y >> 16)   + bf2f(b.y >> 16)   + bf2f(c.y >> 16)));
    ((float4*)acc)[i] = o;
}

static inline size_t align256(size_t x) { return (x + 255) & ~(size_t)255; }

extern "C" void kernel_launch(void* const* d_in, const int* in_sizes, int n_in,
                              void* d_out, int out_size, void* d_ws, size_t ws_size,
                              hipStream_t stream) {
    const int*   edge = (const int*)d_in[0];
    const float* emb0 = (const float*)d_in[1];
    const int E = in_sizes[0] / 2;
    const int N = in_sizes[1] / DIM;
    const int* src = edge;
    const int* dst = edge + E;
    const int NB = (N + BNODE - 1) >> BNODE_SHIFT;   // 391 for N=200000 (<= MAXNB)

    // workspace carve-up (~112 MB)
    char* ws = (char*)d_ws;
    int* bucket_count  = (int*)ws;  ws += align256((size_t)(MAXNB + 1) * sizeof(int));
    int* bucket_base   = (int*)ws;  ws += align256((size_t)(MAXNB + 1) * sizeof(int));
    int* bucket_cursor = (int*)ws;  ws += align256((size_t)(MAXNB + 1) * sizeof(int));
    int* row_start     = (int*)ws;  ws += align256((size_t)(N + 1) * sizeof(int));
    float* dinv        = (float*)ws; ws += align256((size_t)N * sizeof(float));
    float* rs          = (float*)ws; ws += align256((size_t)N * sizeof(float));
    float* di2         = (float*)ws; ws += align256((size_t)N * sizeof(float));
    unsigned int* packed  = (unsigned int*)ws; ws += align256((size_t)E * sizeof(int));
    int* csr_src       = (int*)ws;  ws += align256((size_t)E * sizeof(int));
    unsigned int* SX   = (unsigned int*)ws; ws += align256((size_t)N * DIM / 2 * sizeof(unsigned int) / 2 * 2 + 256);
    // (SX..SZ each hold N*DIM bf16 = N*DIM/2 uints)
    unsigned int* SY   = (unsigned int*)ws; ws += align256((size_t)N * (DIM / 2) * sizeof(unsigned int));
    unsigned int* SZ   = (unsigned int*)ws; ws += align256((size_t)N * (DIM / 2) * sizeof(unsigned int));

    float* out_emb0 = (float*)d_out;
    float* acc      = out_emb0 + (size_t)N * DIM;

    const int blocks_e = (int)(((long long)E + BIN_CHUNK - 1) / BIN_CHUNK);
    const int n4 = N * DIM / 4;

    hipMemsetAsync(bucket_count, 0, (size_t)(MAXNB + 1) * sizeof(int), stream);
    hist_kernel<<<blocks_e, 256, 0, stream>>>(dst, bucket_count, E, NB);
    bucket_scan_kernel<<<1, MAXNB, 0, stream>>>(bucket_count, bucket_base, bucket_cursor,
                                                row_start, NB, N, E);
    bin_kernel<<<blocks_e, 256, 0, stream>>>(src, dst, bucket_cursor, packed, E, NB);
    csr_kernel<<<NB, BNODE, 0, stream>>>(bucket_base, packed, csr_src, row_start,
                                         dinv, rs, di2, N);

    conv0_kernel<<<(n4 + 255) / 256, 256, 0, stream>>>(emb0, dinv, out_emb0, SX, n4);

    const int gthreads = N * 8;
    const int ggrid = (gthreads + 255) / 256;
    gather_kernel<<<ggrid, 256, 0, stream>>>(row_start, csr_src, di2, SX, SY, N);  // S1 = SY
    gather_kernel<<<ggrid, 256, 0, stream>>>(row_start, csr_src, di2, SY, SX, N);  // S2 = SX
    gather_kernel<<<ggrid, 256, 0, stream>>>(row_start, csr_src, di2, SX, SZ, N);  // S3 = SZ

    combine_kernel<<<(n4 + 255) / 256, 256, 0, stream>>>(emb0, rs, SY, SX, SZ, acc, n4);
}